// Round 5
// baseline (293.026 us; speedup 1.0000x reference)
//
#include <hip/hip_runtime.h>
#include <hip/hip_bf16.h>

// ---------------------------------------------------------------------------
// HessianCompatibleMultiHeadAttention on MI355X (gfx950).
// Inputs fp32, output fp32. Internal bf16 MFMA.
// B=2, S=2048, D=1024, H=16, Dk=64.
//   cvt_all:      x, wq, wk, wv, wo  -> bf16
//   gemm_bt<128>: qkv = x_bf @ W^T   (z=0 Q pre-scaled by 0.125*log2e)
//                 BK=64 single-buffer (m97 recipe), XCD-local grid (x=m-tile)
//                 z==2 (V) epilogue writes V^T directly (in-LDS transpose)
//   attn6:        flash attention, q-tile 64, in-block kv-split (2 streams),
//                 32x32x16 MFMA, in-register P (pk2bf + v_permlane32_swap),
//                 T14 async-stage split: reg-prefetch K/V for t+1 after QK^T,
//                 ds_write after raw s_barrier (vmcnt NOT drained at barrier).
//   gemm_bt<64>:  out = ab @ Wo^T + b_o  (fp32 out)
// Workspace planes (8 MB each): 0=Q 1=K 2=V^T 3=x_bf/ab 4..=weights bf16.
// ---------------------------------------------------------------------------

typedef __bf16 bf16x8 __attribute__((ext_vector_type(8)));
typedef float f32x4 __attribute__((ext_vector_type(4)));
typedef float f32x16 __attribute__((ext_vector_type(16)));

__device__ __forceinline__ unsigned short f2bf(float f) {
  union { float f; unsigned int u; } c; c.f = f;
  unsigned int u = c.u;
  return (unsigned short)((u + 0x7FFFu + ((u >> 16) & 1u)) >> 16);
}

// pack two fp32 -> two bf16 (round-half-up) in 3 VALU ops
__device__ __forceinline__ unsigned int pk2bf(float a, float b) {
  union { float f; unsigned int u; } x, y;
  x.f = a; y.f = b;
  return __builtin_amdgcn_perm(y.u + 0x8000u, x.u + 0x8000u, 0x07060302u);
}

__device__ __forceinline__ bf16x8 ld_frag(const unsigned short* p) {
  union { uint4 u; bf16x8 b; } c;
  c.u = *(const uint4*)p;   // 16B aligned -> ds_read_b128
  return c.b;
}

__device__ __forceinline__ uint4 cvt8(const float* __restrict__ p) {
  float4 a = *(const float4*)p;
  float4 b = *(const float4*)(p + 4);
  union { uint4 u; unsigned short s[8]; } r;
  r.s[0] = f2bf(a.x); r.s[1] = f2bf(a.y); r.s[2] = f2bf(a.z); r.s[3] = f2bf(a.w);
  r.s[4] = f2bf(b.x); r.s[5] = f2bf(b.y); r.s[6] = f2bf(b.z); r.s[7] = f2bf(b.w);
  return r.u;
}

// async global->LDS, 16B per lane (lds dest = wave-uniform base + lane*16)
typedef __attribute__((address_space(1))) const unsigned int as1_u32;
typedef __attribute__((address_space(3))) unsigned int as3_u32;
__device__ __forceinline__ void async16(const unsigned short* g,
                                        unsigned short* l) {
  __builtin_amdgcn_global_load_lds(
      (as1_u32*)(unsigned long long)g,
      (as3_u32*)(unsigned int)(unsigned long long)l, 16, 0, 0);
}

// ---------------------------------------------------------------------------
// fp32 -> bf16 conversion (memory-bound). grid (2048, 5).
// ---------------------------------------------------------------------------
__global__ __launch_bounds__(256) void cvt_all(
    const float* __restrict__ s0, const float* __restrict__ s1,
    const float* __restrict__ s2, const float* __restrict__ s3,
    const float* __restrict__ s4,
    unsigned short* __restrict__ d0, unsigned short* __restrict__ d1,
    unsigned short* __restrict__ d2, unsigned short* __restrict__ d3,
    unsigned short* __restrict__ d4) {
  const float* srcs[5] = {s0, s1, s2, s3, s4};
  unsigned short* dsts[5] = {d0, d1, d2, d3, d4};
  const int ns[5] = {4194304, 1048576, 1048576, 1048576, 1048576};
  const int y = blockIdx.y;
  const int idx = (blockIdx.x * 256 + threadIdx.x) * 8;
  if (idx >= ns[y]) return;
  *(uint4*)(dsts[y] + idx) = cvt8(srcs[y] + idx);
}

// ---------------------------------------------------------------------------
// GEMM: C[m][n] = scl * sum_k A[m][k] W[n][k] (+ bias[n]); bf16 in, fp32 acc.
// N=1024, K=1024. BN=128, BK=64 (m97 recipe), single-buffered, 256 thr.
// BM=128: 4 waves 2x2 of 64x64 (qkv path, grid (32,8,3), x = m-tile).
// BM=64:  4 waves 1x4, wave = 64m x 32n (out path, grid (64,8,1)).
// Grid: x = m-tile (fast dispatch dim) -> all 8 n-blocks sharing an A-panel
// land on ONE XCD (linear%8 = mx%8) -> A-panel fetched once into that L2.
// Staging: global_load_lds w=16, 8-row 1KiB chunks; LDS [row][64] with
// slot^(row&7) XOR swizzle pre-applied to the per-lane GLOBAL source
// address (LDS dest linear). Frag reads ds_read_b128, 2-way (free).
// z==2 (V plane): epilogue transposes the 128x128 C-tile in LDS (8-short
// granule XOR swizzle) and writes V^T [bh][d][s] directly into plane 2.
// ---------------------------------------------------------------------------
template <int BM, bool OUT_F32>
__global__ __launch_bounds__(256, 3) void gemm_bt(
    const unsigned short* __restrict__ A,
    const unsigned short* __restrict__ w0,
    const unsigned short* __restrict__ w1,
    const unsigned short* __restrict__ w2,
    const float* __restrict__ bias,
    void* __restrict__ outraw, float z0scale) {
  constexpr int NT = (BM == 128) ? 4 : 2;
  constexpr int RA = BM / 4;  // A rows staged per wave
  const int z = blockIdx.z;
  const unsigned short* W = (z == 0) ? w0 : ((z == 1) ? w1 : w2);
  const float scl = (z == 0) ? z0scale : 1.0f;

  __shared__ unsigned short smem[(BM + 128) * 64];
  unsigned short* a_lds = smem;
  unsigned short* b_lds = smem + BM * 64;

  const int tid = threadIdx.x;
  const int wave = tid >> 6, lane = tid & 63;
  const int quad = lane >> 4, l16 = lane & 15;
  const int wm = (BM == 128) ? (wave >> 1) * 64 : 0;
  const int wn = (BM == 128) ? (wave & 1) * 64 : wave * 32;
  const int bm = blockIdx.x * BM, bn = blockIdx.y * 128;

  // staging: 1 KiB chunk = 8 rows x 64 shorts; lane covers (row8, slot)
  const int r8 = lane >> 3;            // row within chunk (0..7)
  const int sl = (lane & 7) ^ r8;      // inverse-swizzled k-chunk (16B units)
  const unsigned short* ga = A + (size_t)(bm + wave * RA + r8) * 1024 + sl * 8;
  const unsigned short* gb = W + (size_t)(bn + wave * 32 + r8) * 1024 + sl * 8;
  unsigned short* la = &a_lds[wave * RA * 64];
  unsigned short* lb = &b_lds[wave * 32 * 64];

  f32x4 acc[4][NT] = {};

  for (int k0 = 0; k0 < 1024; k0 += 64) {
    // ---- stage A (RA rows/wave) and B (32 rows/wave) ----
#pragma unroll
    for (int c = 0; c < RA / 8; ++c)
      async16(ga + (size_t)c * 8 * 1024, la + c * 512);
#pragma unroll
    for (int c = 0; c < 4; ++c)
      async16(gb + (size_t)c * 8 * 1024, lb + c * 512);
    ga += 64; gb += 64;
    __syncthreads();

    // ---- frag reads: chunk (kk*4+quad) ^ (row&7), row-major [row][64] ----
    bf16x8 af[2][4], bfr[2][NT];
#pragma unroll
    for (int kk = 0; kk < 2; ++kk) {
#pragma unroll
      for (int t = 0; t < 4; ++t) {
        const int row = wm + t * 16 + l16;
        af[kk][t] =
            ld_frag(&a_lds[row * 64 + (((kk * 4 + quad) ^ (row & 7)) * 8)]);
      }
#pragma unroll
      for (int t = 0; t < NT; ++t) {
        const int row = wn + t * 16 + l16;
        bfr[kk][t] =
            ld_frag(&b_lds[row * 64 + (((kk * 4 + quad) ^ (row & 7)) * 8)]);
      }
    }
#pragma unroll
    for (int kk = 0; kk < 2; ++kk)
#pragma unroll
      for (int mt = 0; mt < 4; ++mt)
#pragma unroll
        for (int nt = 0; nt < NT; ++nt)
          acc[mt][nt] = __builtin_amdgcn_mfma_f32_16x16x32_bf16(
              af[kk][mt], bfr[kk][nt], acc[kk ? mt : mt][nt], 0, 0, 0),
          acc[mt][nt] = acc[mt][nt];
    __syncthreads();
  }

  // ---- z==2 (V): transposed epilogue -> V^T [bh][d][s] into plane 2 ----
  if (!OUT_F32 && BM == 128 && z == 2) {
    unsigned short* tt = smem;  // [128 n][128 m] bf16, 8-short-granule swizzle
#pragma unroll
    for (int nt = 0; nt < NT; ++nt) {
      const int nl = wn + nt * 16 + l16;
#pragma unroll
      for (int mt = 0; mt < 4; ++mt) {
        const int ml = wm + mt * 16 + quad * 4;
        union { uint2 u; unsigned short s[4]; } pk;
#pragma unroll
        for (int r = 0; r < 4; ++r) pk.s[r] = f2bf(acc[mt][nt][r]);
        const int g = (ml >> 3) ^ (nl & 7);
        *(uint2*)&tt[nl * 128 + g * 8 + (ml & 7)] = pk.u;
      }
    }
    __syncthreads();
    const int nl = tid >> 1, sc = (tid & 1) * 64;
    const int bb = bm >> 11, s0 = bm & 2047;
    const int hh = (bn >> 6) + (nl >> 6);
    unsigned short* vtp = (unsigned short*)outraw + (size_t)2 * 4096 * 1024 +
                          ((size_t)(bb * 16 + hh)) * 131072 +
                          (size_t)(nl & 63) * 2048 + s0 + sc;
#pragma unroll
    for (int k = 0; k < 8; ++k) {
      const int g = ((sc + k * 8) >> 3) ^ (nl & 7);
      *(uint4*)&vtp[k * 8] = *(const uint4*)&tt[nl * 128 + g * 8];
    }
    return;
  }

  // Epilogue: C/D layout col = lane&15, row = quad*4 + reg  [m89-verified]
#pragma unroll
  for (int nt = 0; nt < NT; ++nt) {
    const int n = bn + wn + nt * 16 + l16;
    const float bv = bias ? bias[n] : 0.0f;
#pragma unroll
    for (int mt = 0; mt < 4; ++mt)
#pragma unroll
      for (int r = 0; r < 4; ++r) {
        const int m = bm + wm + mt * 16 + quad * 4 + r;
        const float v = acc[mt][nt][r] * scl + bv;
        if (OUT_F32)
          ((float*)outraw)[(size_t)z * 4096 * 1024 + (size_t)m * 1024 + n] = v;
        else
          ((unsigned short*)outraw)[(size_t)z * 4096 * 1024 +
                                    (size_t)m * 1024 + n] = f2bf(v);
      }
  }
}

// ---------------------------------------------------------------------------
// Flash attention, q-tile 64, in-block kv-split, no-max exp2 softmax
// (Q pre-scaled by 0.125*log2e).
//
// Structure identical to attn4 (verified 52-54 us) EXCEPT staging:
// T14 async-stage split (m214 v27, +17% there): per tile, issue 8
// global_load_dwordx4 for tile t+1 into registers right after QK^T (latency
// hides under softmax+PV), then raw s_barrier with lgkmcnt(0) ONLY (prefetch
// stays in flight across the barrier), then ds_write_b128 the prefetched
// tile + __syncthreads (vmcnt already drained by the writes' own waits).
// s_setprio(1) wraps both MFMA clusters (m191: +4-7% attn).
// LDS 33280 B, VGPR ~110 (launch_bounds 256,4) -> 4 blocks/CU.
// grid (32 qt, 32 bh) = 1024 blocks.
// ---------------------------------------------------------------------------
__global__ __launch_bounds__(256, 4) void attn6(
    const unsigned short* __restrict__ qkv,   // Q plane at 0, K plane at PL
    const unsigned short* __restrict__ vt_g,  // [32][64][2048] (plane 2)
    unsigned short* __restrict__ ab) {
  constexpr size_t PL = (size_t)4096 * 1024;
  const int qt = blockIdx.x, bh = blockIdx.y;
  const int b = bh >> 4, h = bh & 15;

  __shared__ __align__(16) unsigned short kvs[2][2][64 * 64];  // [ws][K,V][.]
  __shared__ float sm_l[2][2][32];                             // [ws][wq][q]

  const int tid = threadIdx.x;
  const int wave = tid >> 6, lane = tid & 63;
  const int ws = wave >> 1, wq = wave & 1;
  const int hi = lane >> 5, l32 = lane & 31;
  const int row8 = lane >> 3;                  // 0..7 (staging row in chunk)
  const int sl = (lane & 7) ^ (row8 & 7);      // pre-swizzled source slot
  const int swz = (l32 & 7) * 8;               // read-side XOR (shorts)

  // Q fragments (B operand): lane holds Q[q=l32][d = kc*16 + hi*8 + j]
  const unsigned short* qrow =
      qkv + (size_t)(b * 2048 + qt * 64 + wq * 32 + l32) * 1024 + h * 64 +
      hi * 8;
  bf16x8 qf[4];
#pragma unroll
  for (int kc = 0; kc < 4; ++kc) qf[kc] = ld_frag(qrow + kc * 16);

  // staging pointers: per-lane global (swizzled), wave-uniform LDS base.
  // wave wq stages chunks wq*4..wq*4+3 (1 KiB each) of its stream's K and V.
  const unsigned short* gK =
      qkv + PL + (size_t)(b * 2048 + ws * 1024 + wq * 32 + row8) * 1024 +
      h * 64 + sl * 8;
  const unsigned short* gV =
      vt_g + (size_t)bh * 64 * 2048 + (size_t)(wq * 32 + row8) * 2048 +
      ws * 1024 + sl * 8;
  unsigned short* lK = &kvs[ws][0][wq * 4 * 512];
  unsigned short* lV = &kvs[ws][1][wq * 4 * 512];

  f32x16 o_acc[2] = {};
  float l_part = 0.0f;

  // ---- prologue: load + write tile 0 ----
  uint4 pk_[4], pv_[4];
#pragma unroll
  for (int c = 0; c < 4; ++c) {
    pk_[c] = *(const uint4*)(gK + (size_t)c * 8 * 1024);
    pv_[c] = *(const uint4*)(gV + (size_t)c * 8 * 2048);
  }
  gK += 64 * 1024; gV += 64;
#pragma unroll
  for (int c = 0; c < 4; ++c) {
    *(uint4*)(lK + c * 512 + lane * 8) = pk_[c];
    *(uint4*)(lV + c * 512 + lane * 8) = pv_[c];
  }
  __syncthreads();

  for (int t = 0; t < 16; ++t) {
    // ---- QK^T: S^T[kv][q], 2 mb x 4 kc ----
    f32x16 st[2] = {};
    __builtin_amdgcn_s_setprio(1);
#pragma unroll
    for (int mb = 0; mb < 2; ++mb)
#pragma unroll
      for (int kc = 0; kc < 4; ++kc) {
        bf16x8 ak = ld_frag(
            &kvs[ws][0][(mb * 32 + l32) * 64 + (((2 * kc + hi) * 8) ^ swz)]);
        st[mb] = __builtin_amdgcn_mfma_f32_32x32x16_bf16(ak, qf[kc], st[mb],
                                                         0, 0, 0);
      }
    __builtin_amdgcn_s_setprio(0);

    // ---- issue prefetch of tile t+1 (latency hides under SM + PV) ----
    if (t < 15) {
#pragma unroll
      for (int c = 0; c < 4; ++c) {
        pk_[c] = *(const uint4*)(gK + (size_t)c * 8 * 1024);
        pv_[c] = *(const uint4*)(gV + (size_t)c * 8 * 2048);
      }
      gK += 64 * 1024; gV += 64;
      __builtin_amdgcn_sched_barrier(0);  // pin the issue point
    }

    // ---- softmax (no-max exp2) + pack P to bf16 pairs in registers ----
    unsigned int u[2][4][2];
#pragma unroll
    for (int mb = 0; mb < 2; ++mb) {
#pragma unroll
      for (int r = 0; r < 16; ++r) {
        const float p = __builtin_amdgcn_exp2f(st[mb][r]);
        st[mb][r] = p;
        l_part += p;
      }
#pragma unroll
      for (int g = 0; g < 4; ++g) {
        u[mb][g][0] = pk2bf(st[mb][g * 4 + 0], st[mb][g * 4 + 1]);
        u[mb][g][1] = pk2bf(st[mb][g * 4 + 2], st[mb][g * 4 + 3]);
      }
    }

    // ---- PV: O += P.V, A-frags assembled via permlane32_swap ----
#pragma unroll
    for (int ks = 0; ks < 4; ++ks) {
      const int m = ks >> 1, g = (ks & 1) * 2;
      unsigned int a0 = u[m][g][0], b0 = u[m][g + 1][0];
      unsigned int a1 = u[m][g][1], b1 = u[m][g + 1][1];
      // after swap: a' = [a.lo | b.lo], b' = [a.hi | b.hi]
      asm("v_permlane32_swap_b32 %0, %1" : "+v"(a0), "+v"(b0));
      asm("v_permlane32_swap_b32 %0, %1" : "+v"(a1), "+v"(b1));
      union { unsigned int w[4]; bf16x8 f; } pa;
      pa.w[0] = a0; pa.w[1] = a1; pa.w[2] = b0; pa.w[3] = b1;
      __builtin_amdgcn_s_setprio(1);
#pragma unroll
      for (int nb = 0; nb < 2; ++nb) {
        bf16x8 bv = ld_frag(
            &kvs[ws][1][(nb * 32 + l32) * 64 + (((2 * ks + hi) * 8) ^ swz)]);
        o_acc[nb] = __builtin_amdgcn_mfma_f32_32x32x16_bf16(pa.f, bv,
                                                            o_acc[nb], 0, 0, 0);
      }
      __builtin_amdgcn_s_setprio(0);
    }

    // ---- barrier: all LDS reads of tile t done. lgkmcnt ONLY -- the
    // prefetch loads stay in flight across the barrier (T4 principle). ----
    asm volatile("s_waitcnt lgkmcnt(0)" ::: "memory");
    __builtin_amdgcn_sched_barrier(0);
    __builtin_amdgcn_s_barrier();

    if (t < 15) {
      // ---- write prefetched tile t+1 (compiler waits vmcnt here) ----
#pragma unroll
      for (int c = 0; c < 4; ++c) {
        *(uint4*)(lK + c * 512 + lane * 8) = pk_[c];
        *(uint4*)(lV + c * 512 + lane * 8) = pv_[c];
      }
      __syncthreads();  // vmcnt already 0; drains lgkm -> writes visible
    }
  }

  // ---- cross-stream combine: O = (O0+O1) / (l0+l1) ----
  float lsum = l_part + __shfl_xor(l_part, 32);  // full kv-half sum, q=l32

  float* sm_o = (float*)&kvs[0][0][0];  // [2 wq][32 q][64 d] fp32 = 16 KiB
  if (ws == 1) {
#pragma unroll
    for (int nb = 0; nb < 2; ++nb)
#pragma unroll
      for (int r = 0; r < 16; ++r) {
        const int q = (r & 3) + 8 * (r >> 2) + 4 * hi;
        sm_o[wq * 2048 + q * 64 + nb * 32 + l32] = o_acc[nb][r];
      }
  }
  if (lane < 32) sm_l[ws][wq][l32] = lsum;
  __syncthreads();

  if (ws == 0) {
#pragma unroll
    for (int r = 0; r < 16; ++r) {
      const int q = (r & 3) + 8 * (r >> 2) + 4 * hi;
      const float inv = 1.0f / (sm_l[0][wq][q] + sm_l[1][wq][q]);
      const size_t row = (size_t)(b * 2048 + qt * 64 + wq * 32 + q);
#pragma unroll
      for (int nb = 0; nb < 2; ++nb) {
        const float v =
            (o_acc[nb][r] + sm_o[wq * 2048 + q * 64 + nb * 32 + l32]) * inv;
        ab[row * 1024 + h * 64 + nb * 32 + l32] = f2bf(v);
      }
    }
  }
}

// ---------------------------------------------------------------------------
extern "C" void kernel_launch(void* const* d_in, const int* in_sizes, int n_in,
                              void* d_out, int out_size, void* d_ws,
                              size_t ws_size, hipStream_t stream) {
  const float* x  = (const float*)d_in[0];
  const float* wq = (const float*)d_in[1];
  const float* wk = (const float*)d_in[2];
  const float* wv = (const float*)d_in[3];
  const float* wo = (const float*)d_in[4];
  const float* bo = (const float*)d_in[5];

  constexpr size_t PL = (size_t)4096 * 1024;
  unsigned short* qkv = (unsigned short*)d_ws;   // planes 0=Q 1=K 2=V^T
  unsigned short* xb  = qkv + 3 * PL;            // x bf16 (dead after gemm)
  unsigned short* ab  = xb;                      // attn out overlays xb
  unsigned short* wqb = qkv + 4 * PL;
  unsigned short* wkb = wqb + 1024 * 1024;
  unsigned short* wvb = wkb + 1024 * 1024;
  unsigned short* wob = wvb + 1024 * 1024;

  const float QSCALE = 0.18033688011112042f;  // 0.125 * log2(e)

  cvt_all<<<dim3(2048, 5), 256, 0, stream>>>(x, wq, wk, wv, wo,
                                             xb, wqb, wkb, wvb, wob);
  gemm_bt<128, false><<<dim3(32, 8, 3), 256, 0, stream>>>(
      xb, wqb, wkb, wvb, nullptr, qkv, QSCALE);   // z==2 writes V^T (plane 2)
  attn6<<<dim3(32, 32), 256, 0, stream>>>(qkv, qkv + 2 * PL, ab);
  gemm_bt<64, true><<<dim3(64, 8, 1), 256, 0, stream>>>(
      ab, wob, wob, wob, bo, d_out, 1.0f);
}

// Round 6
// 186.532 us; speedup vs baseline: 1.5709x; 1.5709x over previous
//
#include <hip/hip_runtime.h>
#include <hip/hip_bf16.h>

// ---------------------------------------------------------------------------
// HessianCompatibleMultiHeadAttention on MI355X (gfx950).
// Inputs fp32, output fp32. Internal bf16 MFMA.
// B=2, S=2048, D=1024, H=16, Dk=64.
//   cvt_all:      x, wq, wk, wv, wo  -> bf16
//   gemm_bt<128>: qkv = x_bf @ W^T   (z=0 Q pre-scaled by 0.125*log2e)
//                 BK=64 single-buffer (m97 recipe), XCD-local grid (x=m-tile)
//                 z==2 (V) epilogue writes V^T directly (in-LDS transpose)
//   attn4:        flash attention, q-tile 64, in-block kv-split (2 streams),
//                 32x32x16 MFMA, in-register P (pk2bf + v_permlane32_swap),
//                 global_load_lds staging [verified 52.2 us structure],
//                 + T5 s_setprio around MFMA clusters (m191).
//   gemm_bt<64>:  out = ab @ Wo^T + b_o  (fp32 out)
// Workspace planes (8 MB each): 0=Q 1=K 2=V^T 3=x_bf/ab 4..=weights bf16.
// NOTE round-5 lesson: T14 reg-prefetch spilled pk_/pv_ to scratch
// (WRITE_SIZE 8MB->511MB smoking gun) -> reverted to global_load_lds.
// ---------------------------------------------------------------------------

typedef __bf16 bf16x8 __attribute__((ext_vector_type(8)));
typedef float f32x4 __attribute__((ext_vector_type(4)));
typedef float f32x16 __attribute__((ext_vector_type(16)));

__device__ __forceinline__ unsigned short f2bf(float f) {
  union { float f; unsigned int u; } c; c.f = f;
  unsigned int u = c.u;
  return (unsigned short)((u + 0x7FFFu + ((u >> 16) & 1u)) >> 16);
}

// pack two fp32 -> two bf16 (round-half-up) in 3 VALU ops
__device__ __forceinline__ unsigned int pk2bf(float a, float b) {
  union { float f; unsigned int u; } x, y;
  x.f = a; y.f = b;
  return __builtin_amdgcn_perm(y.u + 0x8000u, x.u + 0x8000u, 0x07060302u);
}

__device__ __forceinline__ bf16x8 ld_frag(const unsigned short* p) {
  union { uint4 u; bf16x8 b; } c;
  c.u = *(const uint4*)p;   // 16B aligned -> ds_read_b128
  return c.b;
}

__device__ __forceinline__ uint4 cvt8(const float* __restrict__ p) {
  float4 a = *(const float4*)p;
  float4 b = *(const float4*)(p + 4);
  union { uint4 u; unsigned short s[8]; } r;
  r.s[0] = f2bf(a.x); r.s[1] = f2bf(a.y); r.s[2] = f2bf(a.z); r.s[3] = f2bf(a.w);
  r.s[4] = f2bf(b.x); r.s[5] = f2bf(b.y); r.s[6] = f2bf(b.z); r.s[7] = f2bf(b.w);
  return r.u;
}

// async global->LDS, 16B per lane (lds dest = wave-uniform base + lane*16)
typedef __attribute__((address_space(1))) const unsigned int as1_u32;
typedef __attribute__((address_space(3))) unsigned int as3_u32;
__device__ __forceinline__ void async16(const unsigned short* g,
                                        unsigned short* l) {
  __builtin_amdgcn_global_load_lds(
      (as1_u32*)(unsigned long long)g,
      (as3_u32*)(unsigned int)(unsigned long long)l, 16, 0, 0);
}

// ---------------------------------------------------------------------------
// fp32 -> bf16 conversion (memory-bound). grid (2048, 5).
// ---------------------------------------------------------------------------
__global__ __launch_bounds__(256) void cvt_all(
    const float* __restrict__ s0, const float* __restrict__ s1,
    const float* __restrict__ s2, const float* __restrict__ s3,
    const float* __restrict__ s4,
    unsigned short* __restrict__ d0, unsigned short* __restrict__ d1,
    unsigned short* __restrict__ d2, unsigned short* __restrict__ d3,
    unsigned short* __restrict__ d4) {
  const float* srcs[5] = {s0, s1, s2, s3, s4};
  unsigned short* dsts[5] = {d0, d1, d2, d3, d4};
  const int ns[5] = {4194304, 1048576, 1048576, 1048576, 1048576};
  const int y = blockIdx.y;
  const int idx = (blockIdx.x * 256 + threadIdx.x) * 8;
  if (idx >= ns[y]) return;
  *(uint4*)(dsts[y] + idx) = cvt8(srcs[y] + idx);
}

// ---------------------------------------------------------------------------
// GEMM: C[m][n] = scl * sum_k A[m][k] W[n][k] (+ bias[n]); bf16 in, fp32 acc.
// N=1024, K=1024. BN=128, BK=64 (m97 recipe), single-buffered, 256 thr.
// BM=128: 4 waves 2x2 of 64x64 (qkv path, grid (32,8,3), x = m-tile).
// BM=64:  4 waves 1x4, wave = 64m x 32n (out path, grid (64,8,1)).
// Grid: x = m-tile (fast dispatch dim) -> all 8 n-blocks sharing an A-panel
// land on ONE XCD (linear%8 = mx%8) -> A-panel fetched once into that L2.
// Staging: global_load_lds w=16, 8-row 1KiB chunks; LDS [row][64] with
// slot^(row&7) XOR swizzle pre-applied to the per-lane GLOBAL source
// address (LDS dest linear). Frag reads ds_read_b128, 2-way (free).
// z==2 (V plane): epilogue transposes the 128x128 C-tile in LDS (8-short
// granule XOR swizzle) and writes V^T [bh][d][s] directly into plane 2.
// [V^T epilogue harness-verified in round 5]
// ---------------------------------------------------------------------------
template <int BM, bool OUT_F32>
__global__ __launch_bounds__(256, 3) void gemm_bt(
    const unsigned short* __restrict__ A,
    const unsigned short* __restrict__ w0,
    const unsigned short* __restrict__ w1,
    const unsigned short* __restrict__ w2,
    const float* __restrict__ bias,
    void* __restrict__ outraw, float z0scale) {
  constexpr int NT = (BM == 128) ? 4 : 2;
  constexpr int RA = BM / 4;  // A rows staged per wave
  const int z = blockIdx.z;
  const unsigned short* W = (z == 0) ? w0 : ((z == 1) ? w1 : w2);
  const float scl = (z == 0) ? z0scale : 1.0f;

  __shared__ unsigned short smem[(BM + 128) * 64];
  unsigned short* a_lds = smem;
  unsigned short* b_lds = smem + BM * 64;

  const int tid = threadIdx.x;
  const int wave = tid >> 6, lane = tid & 63;
  const int quad = lane >> 4, l16 = lane & 15;
  const int wm = (BM == 128) ? (wave >> 1) * 64 : 0;
  const int wn = (BM == 128) ? (wave & 1) * 64 : wave * 32;
  const int bm = blockIdx.x * BM, bn = blockIdx.y * 128;

  // staging: 1 KiB chunk = 8 rows x 64 shorts; lane covers (row8, slot)
  const int r8 = lane >> 3;            // row within chunk (0..7)
  const int sl = (lane & 7) ^ r8;      // inverse-swizzled k-chunk (16B units)
  const unsigned short* ga = A + (size_t)(bm + wave * RA + r8) * 1024 + sl * 8;
  const unsigned short* gb = W + (size_t)(bn + wave * 32 + r8) * 1024 + sl * 8;
  unsigned short* la = &a_lds[wave * RA * 64];
  unsigned short* lb = &b_lds[wave * 32 * 64];

  f32x4 acc[4][NT] = {};

  for (int k0 = 0; k0 < 1024; k0 += 64) {
    // ---- stage A (RA rows/wave) and B (32 rows/wave) ----
#pragma unroll
    for (int c = 0; c < RA / 8; ++c)
      async16(ga + (size_t)c * 8 * 1024, la + c * 512);
#pragma unroll
    for (int c = 0; c < 4; ++c)
      async16(gb + (size_t)c * 8 * 1024, lb + c * 512);
    ga += 64; gb += 64;
    __syncthreads();

    // ---- frag reads: chunk (kk*4+quad) ^ (row&7), row-major [row][64] ----
    bf16x8 af[2][4], bfr[2][NT];
#pragma unroll
    for (int kk = 0; kk < 2; ++kk) {
#pragma unroll
      for (int t = 0; t < 4; ++t) {
        const int row = wm + t * 16 + l16;
        af[kk][t] =
            ld_frag(&a_lds[row * 64 + (((kk * 4 + quad) ^ (row & 7)) * 8)]);
      }
#pragma unroll
      for (int t = 0; t < NT; ++t) {
        const int row = wn + t * 16 + l16;
        bfr[kk][t] =
            ld_frag(&b_lds[row * 64 + (((kk * 4 + quad) ^ (row & 7)) * 8)]);
      }
    }
#pragma unroll
    for (int kk = 0; kk < 2; ++kk)
#pragma unroll
      for (int mt = 0; mt < 4; ++mt)
#pragma unroll
        for (int nt = 0; nt < NT; ++nt)
          acc[mt][nt] = __builtin_amdgcn_mfma_f32_16x16x32_bf16(
              af[kk][mt], bfr[kk][nt], acc[mt][nt], 0, 0, 0);
    __syncthreads();
  }

  // ---- z==2 (V): transposed epilogue -> V^T [bh][d][s] into plane 2 ----
  if (!OUT_F32 && BM == 128 && z == 2) {
    unsigned short* tt = smem;  // [128 n][128 m] bf16, 8-short-granule swizzle
#pragma unroll
    for (int nt = 0; nt < NT; ++nt) {
      const int nl = wn + nt * 16 + l16;
#pragma unroll
      for (int mt = 0; mt < 4; ++mt) {
        const int ml = wm + mt * 16 + quad * 4;
        union { uint2 u; unsigned short s[4]; } pk;
#pragma unroll
        for (int r = 0; r < 4; ++r) pk.s[r] = f2bf(acc[mt][nt][r]);
        const int g = (ml >> 3) ^ (nl & 7);
        *(uint2*)&tt[nl * 128 + g * 8 + (ml & 7)] = pk.u;
      }
    }
    __syncthreads();
    const int nl = tid >> 1, sc = (tid & 1) * 64;
    const int bb = bm >> 11, s0 = bm & 2047;
    const int hh = (bn >> 6) + (nl >> 6);
    unsigned short* vtp = (unsigned short*)outraw + (size_t)2 * 4096 * 1024 +
                          ((size_t)(bb * 16 + hh)) * 131072 +
                          (size_t)(nl & 63) * 2048 + s0 + sc;
#pragma unroll
    for (int k = 0; k < 8; ++k) {
      const int g = ((sc + k * 8) >> 3) ^ (nl & 7);
      *(uint4*)&vtp[k * 8] = *(const uint4*)&tt[nl * 128 + g * 8];
    }
    return;
  }

  // Epilogue: C/D layout col = lane&15, row = quad*4 + reg  [m89-verified]
#pragma unroll
  for (int nt = 0; nt < NT; ++nt) {
    const int n = bn + wn + nt * 16 + l16;
    const float bv = bias ? bias[n] : 0.0f;
#pragma unroll
    for (int mt = 0; mt < 4; ++mt)
#pragma unroll
      for (int r = 0; r < 4; ++r) {
        const int m = bm + wm + mt * 16 + quad * 4 + r;
        const float v = acc[mt][nt][r] * scl + bv;
        if (OUT_F32)
          ((float*)outraw)[(size_t)z * 4096 * 1024 + (size_t)m * 1024 + n] = v;
        else
          ((unsigned short*)outraw)[(size_t)z * 4096 * 1024 +
                                    (size_t)m * 1024 + n] = f2bf(v);
      }
  }
}

// ---------------------------------------------------------------------------
// Flash attention, q-tile 64, in-block kv-split, no-max exp2 softmax
// (Q pre-scaled by 0.125*log2e).  [verified 52.2 us structure + T5 setprio]
//
// Block: 256 thr = 4 waves = 2 q-groups (wq) x 2 kv-streams (ws).
//   wave (wq,ws): 32 q rows = qt*64 + wq*32, kv range = ws*1024 .. +1023,
//   iterated in 16 tiles of KVBLK=64.
// MFMA 32x32x16, S^T form (A = K rows, B = Q cols): lane (hi,l32) holds
//   S^T col q=l32, rows kv = 32mb + 4hi + (r&3) + 8(r>>2)  [m74/m101 layout].
// P stays IN REGISTERS: pk2bf pairs -> u[mb][g][p] (kv = 32mb+4hi+8g+2p+{0,1});
//   2x v_permlane32_swap_b32 per k-chunk assembles the PV A-frag
//   (lane needs P[q][16ks+8hi+j]) -- no P LDS round-trip, no P barrier.
// LDS: per stream K tile [64 kv][64 d] + V^T tile [64 d][64 kv], 64-short rows
//   with slot^(row&7) XOR swizzle; staged by global_load_lds w=16 with the
//   inverse swizzle pre-applied to the per-lane GLOBAL source address
//   (LDS dest stays linear). Conflict-free ds_read_b128 frag reads.
// Epilogue: streams combine unnormalized O (fp32) + l through LDS (exp2
//   softmax has no running max -> partials are additive), normalize, store.
// LDS 33280 B, VGPR <=128 (launch_bounds 256,4) -> 4 blocks/CU = 16 waves/CU.
// grid (32 qt, 32 bh) = 1024 blocks.
// ---------------------------------------------------------------------------
__global__ __launch_bounds__(256, 4) void attn4(
    const unsigned short* __restrict__ qkv,   // Q plane at 0, K plane at PL
    const unsigned short* __restrict__ vt_g,  // [32][64][2048] (plane 2)
    unsigned short* __restrict__ ab) {
  constexpr size_t PL = (size_t)4096 * 1024;
  const int qt = blockIdx.x, bh = blockIdx.y;
  const int b = bh >> 4, h = bh & 15;

  __shared__ __align__(16) unsigned short kvs[2][2][64 * 64];  // [ws][K,V][.]
  __shared__ float sm_l[2][2][32];                             // [ws][wq][q]

  const int tid = threadIdx.x;
  const int wave = tid >> 6, lane = tid & 63;
  const int ws = wave >> 1, wq = wave & 1;
  const int hi = lane >> 5, l32 = lane & 31;
  const int row8 = lane >> 3;                  // 0..7 (staging row in chunk)
  const int sl = (lane & 7) ^ (row8 & 7);      // pre-swizzled source slot
  const int swz = (l32 & 7) * 8;               // read-side XOR (shorts)

  // Q fragments (B operand): lane holds Q[q=l32][d = kc*16 + hi*8 + j]
  const unsigned short* qrow =
      qkv + (size_t)(b * 2048 + qt * 64 + wq * 32 + l32) * 1024 + h * 64 +
      hi * 8;
  bf16x8 qf[4];
#pragma unroll
  for (int kc = 0; kc < 4; ++kc) qf[kc] = ld_frag(qrow + kc * 16);

  // staging pointers: per-lane global (swizzled), wave-uniform LDS base.
  // wave wq stages chunks wq*4..wq*4+3 (1 KiB each) of its stream's K and V.
  const unsigned short* gK =
      qkv + PL + (size_t)(b * 2048 + ws * 1024 + wq * 32 + row8) * 1024 +
      h * 64 + sl * 8;
  const unsigned short* gV =
      vt_g + (size_t)bh * 64 * 2048 + (size_t)(wq * 32 + row8) * 2048 +
      ws * 1024 + sl * 8;
  unsigned short* lK = &kvs[ws][0][wq * 4 * 512];
  unsigned short* lV = &kvs[ws][1][wq * 4 * 512];

  f32x16 o_acc[2] = {};
  float l_part = 0.0f;

  for (int t = 0; t < 16; ++t) {
    // ---- stage K,V tiles (64 kv) for this stream ----
#pragma unroll
    for (int c = 0; c < 4; ++c) {
      async16(gK + (size_t)c * 8 * 1024, lK + c * 512);
      async16(gV + (size_t)c * 8 * 2048, lV + c * 512);
    }
    gK += 64 * 1024;  // next 64 kv rows
    gV += 64;         // next 64 kv cols
    __syncthreads();

    // ---- QK^T: S^T[kv][q], 2 mb x 4 kc ----
    f32x16 st[2] = {};
    __builtin_amdgcn_s_setprio(1);
#pragma unroll
    for (int mb = 0; mb < 2; ++mb)
#pragma unroll
      for (int kc = 0; kc < 4; ++kc) {
        bf16x8 ak = ld_frag(
            &kvs[ws][0][(mb * 32 + l32) * 64 + (((2 * kc + hi) * 8) ^ swz)]);
        st[mb] = __builtin_amdgcn_mfma_f32_32x32x16_bf16(ak, qf[kc], st[mb],
                                                         0, 0, 0);
      }
    __builtin_amdgcn_s_setprio(0);

    // ---- softmax (no-max exp2) + pack P to bf16 pairs in registers ----
    unsigned int u[2][4][2];
#pragma unroll
    for (int mb = 0; mb < 2; ++mb) {
#pragma unroll
      for (int r = 0; r < 16; ++r) {
        const float p = __builtin_amdgcn_exp2f(st[mb][r]);
        st[mb][r] = p;
        l_part += p;
      }
#pragma unroll
      for (int g = 0; g < 4; ++g) {
        u[mb][g][0] = pk2bf(st[mb][g * 4 + 0], st[mb][g * 4 + 1]);
        u[mb][g][1] = pk2bf(st[mb][g * 4 + 2], st[mb][g * 4 + 3]);
      }
    }

    // ---- PV: O += P.V, A-frags assembled via permlane32_swap ----
#pragma unroll
    for (int ks = 0; ks < 4; ++ks) {
      const int m = ks >> 1, g = (ks & 1) * 2;
      unsigned int a0 = u[m][g][0], b0 = u[m][g + 1][0];
      unsigned int a1 = u[m][g][1], b1 = u[m][g + 1][1];
      // after swap: a' = [a.lo | b.lo], b' = [a.hi | b.hi]
      asm("v_permlane32_swap_b32 %0, %1" : "+v"(a0), "+v"(b0));
      asm("v_permlane32_swap_b32 %0, %1" : "+v"(a1), "+v"(b1));
      union { unsigned int w[4]; bf16x8 f; } pa;
      pa.w[0] = a0; pa.w[1] = a1; pa.w[2] = b0; pa.w[3] = b1;
      __builtin_amdgcn_s_setprio(1);
#pragma unroll
      for (int nb = 0; nb < 2; ++nb) {
        bf16x8 bv = ld_frag(
            &kvs[ws][1][(nb * 32 + l32) * 64 + (((2 * ks + hi) * 8) ^ swz)]);
        o_acc[nb] = __builtin_amdgcn_mfma_f32_32x32x16_bf16(pa.f, bv,
                                                            o_acc[nb], 0, 0, 0);
      }
      __builtin_amdgcn_s_setprio(0);
    }
    __syncthreads();  // all frag reads done -> restage safe
  }

  // ---- cross-stream combine: O = (O0+O1) / (l0+l1) ----
  float lsum = l_part + __shfl_xor(l_part, 32);  // full kv-half sum, q=l32

  float* sm_o = (float*)&kvs[0][0][0];  // [2 wq][32 q][64 d] fp32 = 16 KiB
  if (ws == 1) {
#pragma unroll
    for (int nb = 0; nb < 2; ++nb)
#pragma unroll
      for (int r = 0; r < 16; ++r) {
        const int q = (r & 3) + 8 * (r >> 2) + 4 * hi;
        sm_o[wq * 2048 + q * 64 + nb * 32 + l32] = o_acc[nb][r];
      }
  }
  if (lane < 32) sm_l[ws][wq][l32] = lsum;
  __syncthreads();

  if (ws == 0) {
#pragma unroll
    for (int r = 0; r < 16; ++r) {
      const int q = (r & 3) + 8 * (r >> 2) + 4 * hi;
      const float inv = 1.0f / (sm_l[0][wq][q] + sm_l[1][wq][q]);
      const size_t row = (size_t)(b * 2048 + qt * 64 + wq * 32 + q);
#pragma unroll
      for (int nb = 0; nb < 2; ++nb) {
        const float v =
            (o_acc[nb][r] + sm_o[wq * 2048 + q * 64 + nb * 32 + l32]) * inv;
        ab[row * 1024 + h * 64 + nb * 32 + l32] = f2bf(v);
      }
    }
  }
}

// ---------------------------------------------------------------------------
extern "C" void kernel_launch(void* const* d_in, const int* in_sizes, int n_in,
                              void* d_out, int out_size, void* d_ws,
                              size_t ws_size, hipStream_t stream) {
  const float* x  = (const float*)d_in[0];
  const float* wq = (const float*)d_in[1];
  const float* wk = (const float*)d_in[2];
  const float* wv = (const float*)d_in[3];
  const float* wo = (const float*)d_in[4];
  const float* bo = (const float*)d_in[5];

  constexpr size_t PL = (size_t)4096 * 1024;
  unsigned short* qkv = (unsigned short*)d_ws;   // planes 0=Q 1=K 2=V^T
  unsigned short* xb  = qkv + 3 * PL;            // x bf16 (dead after gemm)
  unsigned short* ab  = xb;                      // attn out overlays xb
  unsigned short* wqb = qkv + 4 * PL;
  unsigned short* wkb = wqb + 1024 * 1024;
  unsigned short* wvb = wkb + 1024 * 1024;
  unsigned short* wob = wvb + 1024 * 1024;

  const float QSCALE = 0.18033688011112042f;  // 0.125 * log2(e)

  cvt_all<<<dim3(2048, 5), 256, 0, stream>>>(x, wq, wk, wv, wo,
                                             xb, wqb, wkb, wvb, wob);
  gemm_bt<128, false><<<dim3(32, 8, 3), 256, 0, stream>>>(
      xb, wqb, wkb, wvb, nullptr, qkv, QSCALE);   // z==2 writes V^T (plane 2)
  attn4<<<dim3(32, 32), 256, 0, stream>>>(qkv, qkv + 2 * PL, ab);
  gemm_bt<64, true><<<dim3(64, 8, 1), 256, 0, stream>>>(
      ab, wob, wob, wob, bo, d_out, 1.0f);
}

// Round 7
// 179.702 us; speedup vs baseline: 1.6306x; 1.0380x over previous
//
#include <hip/hip_runtime.h>
#include <hip/hip_bf16.h>

// ---------------------------------------------------------------------------
// HessianCompatibleMultiHeadAttention on MI355X (gfx950).
// Inputs fp32, output fp32. Internal bf16 MFMA.
// B=2, S=2048, D=1024, H=16, Dk=64.
//   cvt_all:      x, wq, wk, wv, wo  -> bf16
//   gemm_bt<128>: qkv = x_bf @ W^T   (z=0 Q pre-scaled by 0.125*log2e)
//                 BK=64 single-buffer (m97 recipe), XCD-local grid (x=m-tile)
//                 z==2 (V) epilogue writes V^T directly (in-LDS transpose)
//   attn4:        flash attention, q-tile 64, in-block kv-split (2 streams),
//                 32x32x16 MFMA, in-register P (cvt_pk + v_permlane32_swap),
//                 global_load_lds staging [verified 52.2 us structure,
//                 r6: setprio reverted (null here, lockstep waves)].
//   gemm_bt<128,true>: out = ab @ Wo^T + b_o (fp32), BM=128 (r6: BM=64 had
//                 half the per-wave MFMA density).
// Workspace planes (8 MB each): 0=Q 1=K 2=V^T 3=x_bf/ab 4..=weights bf16.
// Round-5 lesson: T14 reg-prefetch spilled to scratch (WRITE_SIZE 511MB).
// ---------------------------------------------------------------------------

typedef __bf16 bf16x8 __attribute__((ext_vector_type(8)));
typedef float f32x4 __attribute__((ext_vector_type(4)));
typedef float f32x16 __attribute__((ext_vector_type(16)));

__device__ __forceinline__ unsigned short f2bf(float f) {
  union { float f; unsigned int u; } c; c.f = f;
  unsigned int u = c.u;
  return (unsigned short)((u + 0x7FFFu + ((u >> 16) & 1u)) >> 16);
}

// pack two fp32 -> [bf16(a) | bf16(b)<<16] in ONE VALU op (T12 recipe)
__device__ __forceinline__ unsigned int cvtpk(float a, float b) {
  unsigned int r;
  asm("v_cvt_pk_bf16_f32 %0, %1, %2" : "=v"(r) : "v"(a), "v"(b));
  return r;
}

__device__ __forceinline__ bf16x8 ld_frag(const unsigned short* p) {
  union { uint4 u; bf16x8 b; } c;
  c.u = *(const uint4*)p;   // 16B aligned -> ds_read_b128
  return c.b;
}

__device__ __forceinline__ uint4 cvt8(const float* __restrict__ p) {
  float4 a = *(const float4*)p;
  float4 b = *(const float4*)(p + 4);
  union { uint4 u; unsigned short s[8]; } r;
  r.s[0] = f2bf(a.x); r.s[1] = f2bf(a.y); r.s[2] = f2bf(a.z); r.s[3] = f2bf(a.w);
  r.s[4] = f2bf(b.x); r.s[5] = f2bf(b.y); r.s[6] = f2bf(b.z); r.s[7] = f2bf(b.w);
  return r.u;
}

// async global->LDS, 16B per lane (lds dest = wave-uniform base + lane*16)
typedef __attribute__((address_space(1))) const unsigned int as1_u32;
typedef __attribute__((address_space(3))) unsigned int as3_u32;
__device__ __forceinline__ void async16(const unsigned short* g,
                                        unsigned short* l) {
  __builtin_amdgcn_global_load_lds(
      (as1_u32*)(unsigned long long)g,
      (as3_u32*)(unsigned int)(unsigned long long)l, 16, 0, 0);
}

// ---------------------------------------------------------------------------
// fp32 -> bf16 conversion (memory-bound). grid (2048, 5).
// ---------------------------------------------------------------------------
__global__ __launch_bounds__(256) void cvt_all(
    const float* __restrict__ s0, const float* __restrict__ s1,
    const float* __restrict__ s2, const float* __restrict__ s3,
    const float* __restrict__ s4,
    unsigned short* __restrict__ d0, unsigned short* __restrict__ d1,
    unsigned short* __restrict__ d2, unsigned short* __restrict__ d3,
    unsigned short* __restrict__ d4) {
  const float* srcs[5] = {s0, s1, s2, s3, s4};
  unsigned short* dsts[5] = {d0, d1, d2, d3, d4};
  const int ns[5] = {4194304, 1048576, 1048576, 1048576, 1048576};
  const int y = blockIdx.y;
  const int idx = (blockIdx.x * 256 + threadIdx.x) * 8;
  if (idx >= ns[y]) return;
  *(uint4*)(dsts[y] + idx) = cvt8(srcs[y] + idx);
}

// ---------------------------------------------------------------------------
// GEMM: C[m][n] = scl * sum_k A[m][k] W[n][k] (+ bias[n]); bf16 in, fp32 acc.
// N=1024, K=1024. BN=128, BK=64 (m97 recipe), single-buffered, 256 thr.
// BM=128: 4 waves 2x2 of 64x64. qkv path grid (32,8,3); out path (32,8,1).
// Grid: x = m-tile (fast dispatch dim) -> all 8 n-blocks sharing an A-panel
// land on ONE XCD (linear%8 = x%8) -> A-panel fetched once into that L2.
// Staging: global_load_lds w=16, 8-row 1KiB chunks; LDS [row][64] with
// slot^(row&7) XOR swizzle pre-applied to the per-lane GLOBAL source
// address (LDS dest linear). Frag reads ds_read_b128, 2-way (free).
// z==2 (V plane, !OUT_F32): epilogue transposes the 128x128 C-tile in LDS
// (8-short granule XOR swizzle) and writes V^T [bh][d][s] into plane 2.
// [V^T epilogue harness-verified in rounds 5-6]
// ---------------------------------------------------------------------------
template <int BM, bool OUT_F32>
__global__ __launch_bounds__(256, 3) void gemm_bt(
    const unsigned short* __restrict__ A,
    const unsigned short* __restrict__ w0,
    const unsigned short* __restrict__ w1,
    const unsigned short* __restrict__ w2,
    const float* __restrict__ bias,
    void* __restrict__ outraw, float z0scale) {
  constexpr int NT = (BM == 128) ? 4 : 2;
  constexpr int RA = BM / 4;  // A rows staged per wave
  const int z = blockIdx.z;
  const unsigned short* W = (z == 0) ? w0 : ((z == 1) ? w1 : w2);
  const float scl = (z == 0) ? z0scale : 1.0f;

  __shared__ unsigned short smem[(BM + 128) * 64];
  unsigned short* a_lds = smem;
  unsigned short* b_lds = smem + BM * 64;

  const int tid = threadIdx.x;
  const int wave = tid >> 6, lane = tid & 63;
  const int quad = lane >> 4, l16 = lane & 15;
  const int wm = (BM == 128) ? (wave >> 1) * 64 : 0;
  const int wn = (BM == 128) ? (wave & 1) * 64 : wave * 32;
  const int bm = blockIdx.x * BM, bn = blockIdx.y * 128;

  // staging: 1 KiB chunk = 8 rows x 64 shorts; lane covers (row8, slot)
  const int r8 = lane >> 3;            // row within chunk (0..7)
  const int sl = (lane & 7) ^ r8;      // inverse-swizzled k-chunk (16B units)
  const unsigned short* ga = A + (size_t)(bm + wave * RA + r8) * 1024 + sl * 8;
  const unsigned short* gb = W + (size_t)(bn + wave * 32 + r8) * 1024 + sl * 8;
  unsigned short* la = &a_lds[wave * RA * 64];
  unsigned short* lb = &b_lds[wave * 32 * 64];

  f32x4 acc[4][NT] = {};

  for (int k0 = 0; k0 < 1024; k0 += 64) {
    // ---- stage A (RA rows/wave) and B (32 rows/wave) ----
#pragma unroll
    for (int c = 0; c < RA / 8; ++c)
      async16(ga + (size_t)c * 8 * 1024, la + c * 512);
#pragma unroll
    for (int c = 0; c < 4; ++c)
      async16(gb + (size_t)c * 8 * 1024, lb + c * 512);
    ga += 64; gb += 64;
    __syncthreads();

    // ---- frag reads: chunk (kk*4+quad) ^ (row&7), row-major [row][64] ----
    bf16x8 af[2][4], bfr[2][NT];
#pragma unroll
    for (int kk = 0; kk < 2; ++kk) {
#pragma unroll
      for (int t = 0; t < 4; ++t) {
        const int row = wm + t * 16 + l16;
        af[kk][t] =
            ld_frag(&a_lds[row * 64 + (((kk * 4 + quad) ^ (row & 7)) * 8)]);
      }
#pragma unroll
      for (int t = 0; t < NT; ++t) {
        const int row = wn + t * 16 + l16;
        bfr[kk][t] =
            ld_frag(&b_lds[row * 64 + (((kk * 4 + quad) ^ (row & 7)) * 8)]);
      }
    }
#pragma unroll
    for (int kk = 0; kk < 2; ++kk)
#pragma unroll
      for (int mt = 0; mt < 4; ++mt)
#pragma unroll
        for (int nt = 0; nt < NT; ++nt)
          acc[mt][nt] = __builtin_amdgcn_mfma_f32_16x16x32_bf16(
              af[kk][mt], bfr[kk][nt], acc[mt][nt], 0, 0, 0);
    __syncthreads();
  }

  // ---- z==2 (V): transposed epilogue -> V^T [bh][d][s] into plane 2 ----
  if (!OUT_F32 && BM == 128 && z == 2) {
    unsigned short* tt = smem;  // [128 n][128 m] bf16, 8-short-granule swizzle
#pragma unroll
    for (int nt = 0; nt < NT; ++nt) {
      const int nl = wn + nt * 16 + l16;
#pragma unroll
      for (int mt = 0; mt < 4; ++mt) {
        const int ml = wm + mt * 16 + quad * 4;
        union { uint2 u; unsigned short s[4]; } pk;
#pragma unroll
        for (int r = 0; r < 4; ++r) pk.s[r] = f2bf(acc[mt][nt][r]);
        const int g = (ml >> 3) ^ (nl & 7);
        *(uint2*)&tt[nl * 128 + g * 8 + (ml & 7)] = pk.u;
      }
    }
    __syncthreads();
    const int nl = tid >> 1, sc = (tid & 1) * 64;
    const int bb = bm >> 11, s0 = bm & 2047;
    const int hh = (bn >> 6) + (nl >> 6);
    unsigned short* vtp = (unsigned short*)outraw + (size_t)2 * 4096 * 1024 +
                          ((size_t)(bb * 16 + hh)) * 131072 +
                          (size_t)(nl & 63) * 2048 + s0 + sc;
#pragma unroll
    for (int k = 0; k < 8; ++k) {
      const int g = ((sc + k * 8) >> 3) ^ (nl & 7);
      *(uint4*)&vtp[k * 8] = *(const uint4*)&tt[nl * 128 + g * 8];
    }
    return;
  }

  // Epilogue: C/D layout col = lane&15, row = quad*4 + reg  [m89-verified]
#pragma unroll
  for (int nt = 0; nt < NT; ++nt) {
    const int n = bn + wn + nt * 16 + l16;
    const float bv = bias ? bias[n] : 0.0f;
#pragma unroll
    for (int mt = 0; mt < 4; ++mt)
#pragma unroll
      for (int r = 0; r < 4; ++r) {
        const int m = bm + wm + mt * 16 + quad * 4 + r;
        const float v = acc[mt][nt][r] * scl + bv;
        if (OUT_F32)
          ((float*)outraw)[(size_t)z * 4096 * 1024 + (size_t)m * 1024 + n] = v;
        else
          ((unsigned short*)outraw)[(size_t)z * 4096 * 1024 +
                                    (size_t)m * 1024 + n] = f2bf(v);
      }
  }
}

// ---------------------------------------------------------------------------
// Flash attention, q-tile 64, in-block kv-split, no-max exp2 softmax
// (Q pre-scaled by 0.125*log2e).  [round-3 verified structure; setprio
// removed (r6 null); pk2bf -> v_cvt_pk_bf16_f32 (T12, 1 VALU vs 3)]
//
// Block: 256 thr = 4 waves = 2 q-groups (wq) x 2 kv-streams (ws).
//   wave (wq,ws): 32 q rows = qt*64 + wq*32, kv range = ws*1024 .. +1023,
//   iterated in 16 tiles of KVBLK=64.
// MFMA 32x32x16, S^T form (A = K rows, B = Q cols): lane (hi,l32) holds
//   S^T col q=l32, rows kv = 32mb + 4hi + (r&3) + 8(r>>2)  [m74/m101 layout].
// P stays IN REGISTERS: cvt_pk pairs -> u[mb][g][p] (kv = 32mb+4hi+8g+2p+{0,1});
//   2x v_permlane32_swap_b32 per k-chunk assembles the PV A-frag
//   (lane needs P[q][16ks+8hi+j]) -- no P LDS round-trip, no P barrier.
// LDS: per stream K tile [64 kv][64 d] + V^T tile [64 d][64 kv], 64-short rows
//   with slot^(row&7) XOR swizzle; staged by global_load_lds w=16 with the
//   inverse swizzle pre-applied to the per-lane GLOBAL source address
//   (LDS dest stays linear). Conflict-free ds_read_b128 frag reads.
// Epilogue: streams combine unnormalized O (fp32) + l through LDS (exp2
//   softmax has no running max -> partials are additive), normalize, store.
// LDS 33280 B, VGPR <=128 (launch_bounds 256,4) -> 4 blocks/CU = 16 waves/CU.
// grid (32 qt, 32 bh) = 1024 blocks.
// ---------------------------------------------------------------------------
__global__ __launch_bounds__(256, 4) void attn4(
    const unsigned short* __restrict__ qkv,   // Q plane at 0, K plane at PL
    const unsigned short* __restrict__ vt_g,  // [32][64][2048] (plane 2)
    unsigned short* __restrict__ ab) {
  constexpr size_t PL = (size_t)4096 * 1024;
  const int qt = blockIdx.x, bh = blockIdx.y;
  const int b = bh >> 4, h = bh & 15;

  __shared__ __align__(16) unsigned short kvs[2][2][64 * 64];  // [ws][K,V][.]
  __shared__ float sm_l[2][2][32];                             // [ws][wq][q]

  const int tid = threadIdx.x;
  const int wave = tid >> 6, lane = tid & 63;
  const int ws = wave >> 1, wq = wave & 1;
  const int hi = lane >> 5, l32 = lane & 31;
  const int row8 = lane >> 3;                  // 0..7 (staging row in chunk)
  const int sl = (lane & 7) ^ (row8 & 7);      // pre-swizzled source slot
  const int swz = (l32 & 7) * 8;               // read-side XOR (shorts)

  // Q fragments (B operand): lane holds Q[q=l32][d = kc*16 + hi*8 + j]
  const unsigned short* qrow =
      qkv + (size_t)(b * 2048 + qt * 64 + wq * 32 + l32) * 1024 + h * 64 +
      hi * 8;
  bf16x8 qf[4];
#pragma unroll
  for (int kc = 0; kc < 4; ++kc) qf[kc] = ld_frag(qrow + kc * 16);

  // staging pointers: per-lane global (swizzled), wave-uniform LDS base.
  // wave wq stages chunks wq*4..wq*4+3 (1 KiB each) of its stream's K and V.
  const unsigned short* gK =
      qkv + PL + (size_t)(b * 2048 + ws * 1024 + wq * 32 + row8) * 1024 +
      h * 64 + sl * 8;
  const unsigned short* gV =
      vt_g + (size_t)bh * 64 * 2048 + (size_t)(wq * 32 + row8) * 2048 +
      ws * 1024 + sl * 8;
  unsigned short* lK = &kvs[ws][0][wq * 4 * 512];
  unsigned short* lV = &kvs[ws][1][wq * 4 * 512];

  f32x16 o_acc[2] = {};
  float l_part = 0.0f;

  for (int t = 0; t < 16; ++t) {
    // ---- stage K,V tiles (64 kv) for this stream ----
#pragma unroll
    for (int c = 0; c < 4; ++c) {
      async16(gK + (size_t)c * 8 * 1024, lK + c * 512);
      async16(gV + (size_t)c * 8 * 2048, lV + c * 512);
    }
    gK += 64 * 1024;  // next 64 kv rows
    gV += 64;         // next 64 kv cols
    __syncthreads();

    // ---- QK^T: S^T[kv][q], 2 mb x 4 kc ----
    f32x16 st[2] = {};
#pragma unroll
    for (int mb = 0; mb < 2; ++mb)
#pragma unroll
      for (int kc = 0; kc < 4; ++kc) {
        bf16x8 ak = ld_frag(
            &kvs[ws][0][(mb * 32 + l32) * 64 + (((2 * kc + hi) * 8) ^ swz)]);
        st[mb] = __builtin_amdgcn_mfma_f32_32x32x16_bf16(ak, qf[kc], st[mb],
                                                         0, 0, 0);
      }

    // ---- softmax (no-max exp2) + pack P to bf16 pairs in registers ----
    unsigned int u[2][4][2];
#pragma unroll
    for (int mb = 0; mb < 2; ++mb) {
#pragma unroll
      for (int r = 0; r < 16; ++r) {
        const float p = __builtin_amdgcn_exp2f(st[mb][r]);
        st[mb][r] = p;
        l_part += p;
      }
#pragma unroll
      for (int g = 0; g < 4; ++g) {
        u[mb][g][0] = cvtpk(st[mb][g * 4 + 0], st[mb][g * 4 + 1]);
        u[mb][g][1] = cvtpk(st[mb][g * 4 + 2], st[mb][g * 4 + 3]);
      }
    }

    // ---- PV: O += P.V, A-frags assembled via permlane32_swap ----
#pragma unroll
    for (int ks = 0; ks < 4; ++ks) {
      const int m = ks >> 1, g = (ks & 1) * 2;
      unsigned int a0 = u[m][g][0], b0 = u[m][g + 1][0];
      unsigned int a1 = u[m][g][1], b1 = u[m][g + 1][1];
      // after swap: a' = [a.lo | b.lo], b' = [a.hi | b.hi]
      asm("v_permlane32_swap_b32 %0, %1" : "+v"(a0), "+v"(b0));
      asm("v_permlane32_swap_b32 %0, %1" : "+v"(a1), "+v"(b1));
      union { unsigned int w[4]; bf16x8 f; } pa;
      pa.w[0] = a0; pa.w[1] = a1; pa.w[2] = b0; pa.w[3] = b1;
#pragma unroll
      for (int nb = 0; nb < 2; ++nb) {
        bf16x8 bv = ld_frag(
            &kvs[ws][1][(nb * 32 + l32) * 64 + (((2 * ks + hi) * 8) ^ swz)]);
        o_acc[nb] = __builtin_amdgcn_mfma_f32_32x32x16_bf16(pa.f, bv,
                                                            o_acc[nb], 0, 0, 0);
      }
    }
    __syncthreads();  // all frag reads done -> restage safe
  }

  // ---- cross-stream combine: O = (O0+O1) / (l0+l1) ----
  float lsum = l_part + __shfl_xor(l_part, 32);  // full kv-half sum, q=l32

  float* sm_o = (float*)&kvs[0][0][0];  // [2 wq][32 q][64 d] fp32 = 16 KiB
  if (ws == 1) {
#pragma unroll
    for (int nb = 0; nb < 2; ++nb)
#pragma unroll
      for (int r = 0; r < 16; ++r) {
        const int q = (r & 3) + 8 * (r >> 2) + 4 * hi;
        sm_o[wq * 2048 + q * 64 + nb * 32 + l32] = o_acc[nb][r];
      }
  }
  if (lane < 32) sm_l[ws][wq][l32] = lsum;
  __syncthreads();

  if (ws == 0) {
#pragma unroll
    for (int r = 0; r < 16; ++r) {
      const int q = (r & 3) + 8 * (r >> 2) + 4 * hi;
      const float inv = 1.0f / (sm_l[0][wq][q] + sm_l[1][wq][q]);
      const size_t row = (size_t)(b * 2048 + qt * 64 + wq * 32 + q);
#pragma unroll
      for (int nb = 0; nb < 2; ++nb) {
        const float v =
            (o_acc[nb][r] + sm_o[wq * 2048 + q * 64 + nb * 32 + l32]) * inv;
        ab[row * 1024 + h * 64 + nb * 32 + l32] = f2bf(v);
      }
    }
  }
}

// ---------------------------------------------------------------------------
extern "C" void kernel_launch(void* const* d_in, const int* in_sizes, int n_in,
                              void* d_out, int out_size, void* d_ws,
                              size_t ws_size, hipStream_t stream) {
  const float* x  = (const float*)d_in[0];
  const float* wq = (const float*)d_in[1];
  const float* wk = (const float*)d_in[2];
  const float* wv = (const float*)d_in[3];
  const float* wo = (const float*)d_in[4];
  const float* bo = (const float*)d_in[5];

  constexpr size_t PL = (size_t)4096 * 1024;
  unsigned short* qkv = (unsigned short*)d_ws;   // planes 0=Q 1=K 2=V^T
  unsigned short* xb  = qkv + 3 * PL;            // x bf16 (dead after gemm)
  unsigned short* ab  = xb;                      // attn out overlays xb
  unsigned short* wqb = qkv + 4 * PL;
  unsigned short* wkb = wqb + 1024 * 1024;
  unsigned short* wvb = wkb + 1024 * 1024;
  unsigned short* wob = wvb + 1024 * 1024;

  const float QSCALE = 0.18033688011112042f;  // 0.125 * log2(e)

  cvt_all<<<dim3(2048, 5), 256, 0, stream>>>(x, wq, wk, wv, wo,
                                             xb, wqb, wkb, wvb, wob);
  gemm_bt<128, false><<<dim3(32, 8, 3), 256, 0, stream>>>(
      xb, wqb, wkb, wvb, nullptr, qkv, QSCALE);   // z==2 writes V^T (plane 2)
  attn4<<<dim3(32, 32), 256, 0, stream>>>(qkv, qkv + 2 * PL, ab);
  gemm_bt<128, true><<<dim3(32, 8, 1), 256, 0, stream>>>(
      ab, wob, wob, wob, bo, d_out, 1.0f);
}